// Round 6
// baseline (163.683 us; speedup 1.0000x reference)
//
#include <hip/hip_runtime.h>

// CommSlave — Round 6: one-generation design. Block = 128 thr = 2 waves;
// wave = 16 rows = 2 attention groups, ALL LDS wave-local. 17.9 KB LDS/block
// -> 9 blocks/CU resident = 18 waves; total work = 16 waves/CU => every wave
// co-resident, no block generations. bf16 packs via v_cvt_pk_bf16_f32.
// Weights prepped (bf16, pre-transposed B-frag layouts) by a tiny prep kernel.
// Fragment maps (verified r4/r5): A[m=lane&15][k=quad*8+j]; B stored [n][k];
// C/D col=lane&15, row=quad*4+reg.

#define NACT 14
#define BTOT 65536

typedef unsigned int  u32;
typedef unsigned short u16;
using short8 = __attribute__((ext_vector_type(8))) short;
using f32x4  = __attribute__((ext_vector_type(4))) float;

// ---- prepped weight images (u16 offsets), module device memory ----
#define ENCB 0        // [n=64][k pad 264]  B[k][n] = encW[k][n]
#define WIHB 16896    // [n=192][k pad 72]  B[k][n] = Wih[n][k]
#define WHHB 30720    // [n=192][k pad 72]
#define QKVB 44544    // [n=96][k pad 72]   q^T/sqrt(32), k^T, v^T
#define DECB 51456    // [n=16][k pad 104]  B[k][n] = decW[k][n], zero-padded
#define WTOT 53120

__device__ u16   g_wbuf[WTOT];
__device__ float g_bias[256];   // r: bih+bhh, z: bih+bhh, n_i: bih, n_h: bhh

__device__ __forceinline__ u32 f2bf_rne(float f){
  u32 x = __float_as_uint(f);
  return (x + 0x7fffu + ((x >> 16) & 1u)) >> 16;
}
__device__ __forceinline__ u32 pk2(float a, float b){     // gfx950 packed cvt
  u32 d;
  asm("v_cvt_pk_bf16_f32 %0, %1, %2" : "=v"(d) : "v"(a), "v"(b));
  return d;
}
__device__ __forceinline__ float blo(u32 u){ return __uint_as_float(u << 16); }
__device__ __forceinline__ float bhi(u32 u){ return __uint_as_float(u & 0xffff0000u); }
__device__ __forceinline__ float sigm(float x){ return 1.0f / (1.0f + __expf(-x)); }
__device__ __forceinline__ float tanhp(float x){ return 1.0f - 2.0f / (__expf(2.0f * x) + 1.0f); }
__device__ __forceinline__ short8 as_s8(uint4 v){ union { uint4 u; short8 s; } x; x.u = v; return x.s; }

#define MFMA16(a,b,c) __builtin_amdgcn_mfma_f32_16x16x32_bf16((a),(b),(c),0,0,0)

// ======================= prep ================================================
__global__ void prep(const float* __restrict__ encW, const float* __restrict__ Wih,
                     const float* __restrict__ Whh,  const float* __restrict__ qW,
                     const float* __restrict__ kW,   const float* __restrict__ vW,
                     const float* __restrict__ decW, const float* __restrict__ bih,
                     const float* __restrict__ bhh)
{
  int i = blockIdx.x * 256 + threadIdx.x;
  if (blockIdx.x == 0) {
    int n = threadIdx.x & 63, g = threadIdx.x >> 6;
    float v;
    if      (g == 0) v = bih[n]       + bhh[n];
    else if (g == 1) v = bih[64 + n]  + bhh[64 + n];
    else if (g == 2) v = bih[128 + n];
    else             v = bhh[128 + n];
    g_bias[threadIdx.x] = v;
  }
  if (i >= WTOT) return;
  float val = 0.f;
  if (i < WIHB)      { int n = i / 264, k = i % 264;            if (k < 256) val = encW[k * 64 + n]; }
  else if (i < WHHB) { int j = i - WIHB; int n = j / 72, k = j % 72; if (k < 64) val = Wih[n * 64 + k]; }
  else if (i < QKVB) { int j = i - WHHB; int n = j / 72, k = j % 72; if (k < 64) val = Whh[n * 64 + k]; }
  else if (i < DECB) { int j = i - QKVB; int n = j / 72, k = j % 72;
    if (k < 64) { int m = n >> 5, nn = n & 31;
      val = (m == 0) ? qW[k * 32 + nn] * 0.17677669529663687f
          : (m == 1) ? kW[k * 32 + nn] : vW[k * 32 + nn]; } }
  else { int j = i - DECB; int n = j / 104, k = j % 104; if (n < 14 && k < 96) val = decW[k * 14 + n]; }
  g_wbuf[i] = (u16)f2bf_rne(val);
}

// ======================= main ================================================
// LDS/block (17920 B): X bf16 [32][72] @u16 0  (x; cols 32-63 reused for v,
// cols 0-31 for xatt) ; H bf16 [32][72] @u16 2304 (hid, then h_out) ;
// S fp32 [16][68] per wave @byte 9216 (+4352B/wave): transpose scratch,
// then q@0-31, k@32-63 (p overwrites q cols 0-7).
__global__ __launch_bounds__(128, 4)
void commslave_main(const float* __restrict__ obs,  const float* __restrict__ hid,
                    const float* __restrict__ encb, const float* __restrict__ vb,
                    const float* __restrict__ decb, float* __restrict__ out)
{
  __shared__ __align__(16) u16 ldsU[8960];

  const int tid  = threadIdx.x;
  const int lane = tid & 63;
  const int w    = tid >> 6;
  const int quad = lane >> 4;
  const int l16  = lane & 15;
  const int M0   = 16 * w;                      // block-local row base
  const int gr   = blockIdx.x * 32 + M0;        // global row base of wave
  float* Sf = (float*)(ldsU + 4608) + w * (16 * 68);

  // ---- stage hid rows gr..gr+15 -> H bf16 (wave-local) ----
  #pragma unroll
  for (int i = 0; i < 4; i++) {
    int c = lane + 64 * i;                      // 0..255
    int lr = c >> 4, c4 = c & 15;
    float4 v = ((const float4*)hid)[(size_t)(gr + lr) * 16 + c4];
    *(uint2*)&ldsU[2304 + (M0 + lr) * 72 + c4 * 4] = make_uint2(pk2(v.x, v.y), pk2(v.z, v.w));
  }

  // ---- enc: x = relu(obs @ encW + encb) ----
  f32x4 ce[4];
  #pragma unroll
  for (int t = 0; t < 4; t++) { float bv = encb[16 * t + l16]; ce[t] = (f32x4){bv, bv, bv, bv}; }
  #pragma unroll
  for (int ks = 0; ks < 8; ks++) {
    const float* ap = obs + (size_t)(gr + l16) * 256 + ks * 32 + quad * 8;
    float4 a0 = *(const float4*)ap, a1 = *(const float4*)(ap + 4);
    short8 a = as_s8(make_uint4(pk2(a0.x, a0.y), pk2(a0.z, a0.w), pk2(a1.x, a1.y), pk2(a1.z, a1.w)));
    #pragma unroll
    for (int t = 0; t < 4; t++) {
      short8 b = as_s8(*(const uint4*)&g_wbuf[ENCB + (16 * t + l16) * 264 + ks * 32 + quad * 8]);
      ce[t] = MFMA16(a, b, ce[t]);
    }
  }
  #pragma unroll
  for (int t = 0; t < 4; t++)
    #pragma unroll
    for (int r = 0; r < 4; r++)
      Sf[(quad * 4 + r) * 68 + 16 * t + l16] = fmaxf(ce[t][r], 0.f);
  #pragma unroll
  for (int i = 0; i < 2; i++) {                 // transpose-pack x -> X
    int c = lane + 64 * i, lr = c >> 3, j = c & 7;
    const float* sp = &Sf[lr * 68 + 8 * j];
    float4 v0 = *(const float4*)sp, v1 = *(const float4*)(sp + 4);
    *(uint4*)&ldsU[(M0 + lr) * 72 + 8 * j] =
        make_uint4(pk2(v0.x, v0.y), pk2(v0.z, v0.w), pk2(v1.x, v1.y), pk2(v1.z, v1.w));
  }
  __syncthreads();   // X/H uint writes -> short8 frag reads

  // ---- GRU ----
  short8 ax[2], ah[2];
  #pragma unroll
  for (int ks = 0; ks < 2; ks++) {
    ax[ks] = *(const short8*)&ldsU[(M0 + l16) * 72 + ks * 32 + quad * 8];
    ah[ks] = *(const short8*)&ldsU[2304 + (M0 + l16) * 72 + ks * 32 + quad * 8];
  }
  #pragma unroll
  for (int u = 0; u < 4; u++) {
    f32x4 g6[6];
    #pragma unroll
    for (int t = 0; t < 6; t++) g6[t] = (f32x4){0.f, 0.f, 0.f, 0.f};
    #pragma unroll
    for (int g = 0; g < 3; g++) {
      int row = 64 * g + 16 * u + l16;
      #pragma unroll
      for (int ks = 0; ks < 2; ks++) {
        short8 bi = as_s8(*(const uint4*)&g_wbuf[WIHB + row * 72 + ks * 32 + quad * 8]);
        g6[g] = MFMA16(ax[ks], bi, g6[g]);
        short8 bh = as_s8(*(const uint4*)&g_wbuf[WHHB + row * 72 + ks * 32 + quad * 8]);
        g6[3 + g] = MFMA16(ah[ks], bh, g6[3 + g]);
      }
    }
    int nc = 16 * u + l16;
    float brz = g_bias[nc], bzz = g_bias[64 + nc], bni = g_bias[128 + nc], bnh = g_bias[192 + nc];
    #pragma unroll
    for (int r = 0; r < 4; r++) {
      float hp = blo(ldsU[2304 + (M0 + quad * 4 + r) * 72 + nc]);
      float rg = sigm(g6[0][r] + g6[3][r] + brz);
      float zg = sigm(g6[1][r] + g6[4][r] + bzz);
      float nn = tanhp(g6[2][r] + bni + rg * (g6[5][r] + bnh));
      Sf[(quad * 4 + r) * 68 + nc] = (1.f - zg) * nn + zg * hp;
    }
  }
  #pragma unroll
  for (int i = 0; i < 2; i++) {                 // transpose-pack h_out -> H
    int c = lane + 64 * i, lr = c >> 3, j = c & 7;
    const float* sp = &Sf[lr * 68 + 8 * j];
    float4 v0 = *(const float4*)sp, v1 = *(const float4*)(sp + 4);
    *(uint4*)&ldsU[2304 + (M0 + lr) * 72 + 8 * j] =
        make_uint4(pk2(v0.x, v0.y), pk2(v0.z, v0.w), pk2(v1.x, v1.y), pk2(v1.z, v1.w));
  }
  __syncthreads();   // H h_out writes -> short8 reads

  // ---- q,k,v ----
  short8 hx[2];
  #pragma unroll
  for (int ks = 0; ks < 2; ks++)
    hx[ks] = *(const short8*)&ldsU[2304 + (M0 + l16) * 72 + ks * 32 + quad * 8];
  f32x4 cq[6];
  #pragma unroll
  for (int t = 0; t < 6; t++) {
    float bv = (t >= 4) ? vb[16 * (t - 4) + l16] : 0.f;
    cq[t] = (f32x4){bv, bv, bv, bv};
  }
  #pragma unroll
  for (int ks = 0; ks < 2; ks++)
    #pragma unroll
    for (int t = 0; t < 6; t++) {
      short8 b = as_s8(*(const uint4*)&g_wbuf[QKVB + (16 * t + l16) * 72 + ks * 32 + quad * 8]);
      cq[t] = MFMA16(hx[ks], b, cq[t]);
    }
  #pragma unroll
  for (int t = 0; t < 4; t++)                   // q (pre-scaled) cols 0-31, k cols 32-63
    #pragma unroll
    for (int r = 0; r < 4; r++)
      Sf[(quad * 4 + r) * 68 + 16 * t + l16] = cq[t][r];
  #pragma unroll
  for (int t = 4; t < 6; t++)                   // v -> X cols 32..63 bf16
    #pragma unroll
    for (int r = 0; r < 4; r++)
      ldsU[(M0 + quad * 4 + r) * 72 + 32 + 16 * (t - 4) + l16] =
          (u16)pk2(fmaxf(cq[t][r], 0.f), 0.f);
  __syncthreads();   // v u16 writes -> uint4 reads in attention

  // ---- attention (wave-local, 4 lanes/row) ----
  {
    const int r_l = lane >> 2, s4 = lane & 3;
    const int gb = r_l & 8, ri = r_l & 7;
    const float* fq = &Sf[r_l * 68];
    float sc[2];
    #pragma unroll
    for (int jj = 0; jj < 2; jj++) {
      int j = s4 + 4 * jj;
      const float* fk = &Sf[(gb + j) * 68 + 32];
      float d = 0.f;
      #pragma unroll
      for (int a4 = 0; a4 < 32; a4 += 4) {
        float4 q4 = *(const float4*)&fq[a4];
        float4 k4 = *(const float4*)&fk[a4];
        d += q4.x * k4.x + q4.y * k4.y + q4.z * k4.z + q4.w * k4.w;
      }
      sc[jj] = (j == ri) ? -1e30f : d;
    }
    float m = fmaxf(sc[0], sc[1]);
    m = fmaxf(m, __shfl_xor(m, 1));
    m = fmaxf(m, __shfl_xor(m, 2));
    float p0 = (s4     == ri) ? 0.f : __expf(sc[0] - m);
    float p1 = (s4 + 4 == ri) ? 0.f : __expf(sc[1] - m);
    float sum = p0 + p1;
    sum += __shfl_xor(sum, 1);
    sum += __shfl_xor(sum, 2);
    float inv = 1.f / sum;
    Sf[r_l * 68 + s4]     = p0 * inv;           // p overwrites q cols 0..7
    Sf[r_l * 68 + 4 + s4] = p1 * inv;
    float xa[8] = {0, 0, 0, 0, 0, 0, 0, 0};
    #pragma unroll
    for (int j = 0; j < 8; j++) {
      float aj = Sf[r_l * 68 + j];
      uint4 uv = *(const uint4*)&ldsU[(M0 + gb + j) * 72 + 32 + 8 * s4];
      xa[0] += aj * blo(uv.x); xa[1] += aj * bhi(uv.x);
      xa[2] += aj * blo(uv.y); xa[3] += aj * bhi(uv.y);
      xa[4] += aj * blo(uv.z); xa[5] += aj * bhi(uv.z);
      xa[6] += aj * blo(uv.w); xa[7] += aj * bhi(uv.w);
    }
    *(uint4*)&ldsU[(M0 + r_l) * 72 + 8 * s4] =  // xatt -> X cols 0..31
        make_uint4(pk2(xa[0], xa[1]), pk2(xa[2], xa[3]), pk2(xa[4], xa[5]), pk2(xa[6], xa[7]));
  }
  __syncthreads();   // xatt uint4 writes -> short8 reads

  // ---- dec: [h_out | xatt] @ decW + decb ----
  {
    float db = (l16 < NACT) ? decb[l16] : 0.f;
    f32x4 co = (f32x4){db, db, db, db};
    #pragma unroll
    for (int ks = 0; ks < 2; ks++) {
      short8 a = *(const short8*)&ldsU[2304 + (M0 + l16) * 72 + ks * 32 + quad * 8];
      short8 b = as_s8(*(const uint4*)&g_wbuf[DECB + l16 * 104 + ks * 32 + quad * 8]);
      co = MFMA16(a, b, co);
    }
    short8 a2 = *(const short8*)&ldsU[(M0 + l16) * 72 + quad * 8];
    short8 b2 = as_s8(*(const uint4*)&g_wbuf[DECB + l16 * 104 + 64 + quad * 8]);
    co = MFMA16(a2, b2, co);
    if (l16 < NACT) {
      #pragma unroll
      for (int r = 0; r < 4; r++)
        out[(size_t)(gr + quad * 4 + r) * NACT + l16] = co[r];
    }
  }

  // ---- h_out fp32 global store (from H bf16; no barrier after) ----
  {
    float* outH = out + (size_t)BTOT * NACT;
    #pragma unroll
    for (int i = 0; i < 2; i++) {
      int c = lane + 64 * i, lr = c >> 3, j = c & 7;
      uint4 u = *(const uint4*)&ldsU[2304 + (M0 + lr) * 72 + 8 * j];
      *(float4*)(outH + (size_t)(gr + lr) * 64 + 8 * j) =
          make_float4(blo(u.x), bhi(u.x), blo(u.y), bhi(u.y));
      *(float4*)(outH + (size_t)(gr + lr) * 64 + 8 * j + 4) =
          make_float4(blo(u.z), bhi(u.z), blo(u.w), bhi(u.w));
    }
  }
}

extern "C" void kernel_launch(void* const* d_in, const int* in_sizes, int n_in,
                              void* d_out, int out_size, void* d_ws, size_t ws_size,
                              hipStream_t stream) {
  (void)in_sizes; (void)n_in; (void)d_ws; (void)ws_size; (void)out_size;
  const float* obs  = (const float*)d_in[0];
  const float* hid  = (const float*)d_in[1];
  const float* encW = (const float*)d_in[2];
  const float* encb = (const float*)d_in[3];
  const float* Wih  = (const float*)d_in[4];
  const float* Whh  = (const float*)d_in[5];
  const float* bih  = (const float*)d_in[6];
  const float* bhh  = (const float*)d_in[7];
  const float* qW   = (const float*)d_in[8];
  const float* kW   = (const float*)d_in[9];
  const float* vW   = (const float*)d_in[10];
  const float* vb   = (const float*)d_in[11];
  const float* decW = (const float*)d_in[12];
  const float* decb = (const float*)d_in[13];
  float* out = (float*)d_out;

  prep<<<(WTOT + 255) / 256, 256, 0, stream>>>(encW, Wih, Whh, qW, kW, vW, decW, bih, bhh);
  commslave_main<<<BTOT / 32, 128, 0, stream>>>(obs, hid, encb, vb, decb, out);
}

// Round 7
// 154.215 us; speedup vs baseline: 1.0614x; 1.0614x over previous
//
#include <hip/hip_runtime.h>

// CommSlave — Round 7: 32 rows/wave (2 m-tiles share every B-frag load),
// 256-VGPR budget for wide load batching. Block = 128 thr = 2 waves = 64 rows.
// Grid = 1024 (4 blocks/CU, all co-resident). Weights prepped to bf16
// B-frag layout in module memory (unchanged from r5/r6).
// Fragment maps (verified r4-r6): A[m=lane&15][k=quad*8+j]; B stored [n][k];
// C/D col=lane&15, row=quad*4+reg.

#define NACT 14
#define BTOT 65536

typedef unsigned int  u32;
typedef unsigned short u16;
using short8 = __attribute__((ext_vector_type(8))) short;
using f32x4  = __attribute__((ext_vector_type(4))) float;

#define ENCB 0        // [n=64][k pad 264]  B[k][n] = encW[k][n]
#define WIHB 16896    // [n=192][k pad 72]  B[k][n] = Wih[n][k]
#define WHHB 30720    // [n=192][k pad 72]
#define QKVB 44544    // [n=96][k pad 72]   q^T/sqrt(32), k^T, v^T
#define DECB 51456    // [n=16][k pad 104]  B[k][n] = decW[k][n], zero-padded
#define WTOT 53120

__device__ u16   g_wbuf[WTOT];
__device__ float g_bias[256];   // r: bih+bhh, z: bih+bhh, n_i: bih, n_h: bhh

__device__ __forceinline__ u32 f2bf_rne(float f){
  u32 x = __float_as_uint(f);
  return (x + 0x7fffu + ((x >> 16) & 1u)) >> 16;
}
__device__ __forceinline__ u32 pk2(float a, float b){
  u32 d;
  asm("v_cvt_pk_bf16_f32 %0, %1, %2" : "=v"(d) : "v"(a), "v"(b));
  return d;
}
__device__ __forceinline__ float blo(u32 u){ return __uint_as_float(u << 16); }
__device__ __forceinline__ float bhi(u32 u){ return __uint_as_float(u & 0xffff0000u); }
__device__ __forceinline__ float sigm(float x){ return 1.0f / (1.0f + __expf(-x)); }
__device__ __forceinline__ float tanhp(float x){ return 1.0f - 2.0f / (__expf(2.0f * x) + 1.0f); }
__device__ __forceinline__ short8 as_s8(uint4 v){ union { uint4 u; short8 s; } x; x.u = v; return x.s; }

#define MFMA16(a,b,c) __builtin_amdgcn_mfma_f32_16x16x32_bf16((a),(b),(c),0,0,0)

// ======================= prep ================================================
__global__ void prep(const float* __restrict__ encW, const float* __restrict__ Wih,
                     const float* __restrict__ Whh,  const float* __restrict__ qW,
                     const float* __restrict__ kW,   const float* __restrict__ vW,
                     const float* __restrict__ decW, const float* __restrict__ bih,
                     const float* __restrict__ bhh)
{
  int i = blockIdx.x * 256 + threadIdx.x;
  if (blockIdx.x == 0) {
    int n = threadIdx.x & 63, g = threadIdx.x >> 6;
    float v;
    if      (g == 0) v = bih[n]       + bhh[n];
    else if (g == 1) v = bih[64 + n]  + bhh[64 + n];
    else if (g == 2) v = bih[128 + n];
    else             v = bhh[128 + n];
    g_bias[threadIdx.x] = v;
  }
  if (i >= WTOT) return;
  float val = 0.f;
  if (i < WIHB)      { int n = i / 264, k = i % 264;            if (k < 256) val = encW[k * 64 + n]; }
  else if (i < WHHB) { int j = i - WIHB; int n = j / 72, k = j % 72; if (k < 64) val = Wih[n * 64 + k]; }
  else if (i < QKVB) { int j = i - WHHB; int n = j / 72, k = j % 72; if (k < 64) val = Whh[n * 64 + k]; }
  else if (i < DECB) { int j = i - QKVB; int n = j / 72, k = j % 72;
    if (k < 64) { int m = n >> 5, nn = n & 31;
      val = (m == 0) ? qW[k * 32 + nn] * 0.17677669529663687f
          : (m == 1) ? kW[k * 32 + nn] : vW[k * 32 + nn]; } }
  else { int j = i - DECB; int n = j / 104, k = j % 104; if (n < 14 && k < 96) val = decW[k * 14 + n]; }
  g_wbuf[i] = (u16)f2bf_rne(val);
}

// ======================= main ================================================
// LDS/block (35840 B): X bf16 [64][72] @u16 0 (x; cols 32-63 v, 0-31 xatt);
// H bf16 [64][72] @u16 4608 (hid -> h_out); Sf fp32 [32][68] per wave
// @byte 18432 + w*8704 (x/h transpose scratch, then q cols 0-31 / k 32-63,
// p overwrites q cols 0-7).
__global__ __launch_bounds__(128, 2)
void commslave_main(const float* __restrict__ obs,  const float* __restrict__ hid,
                    const float* __restrict__ encb, const float* __restrict__ vb,
                    const float* __restrict__ decb, float* __restrict__ out)
{
  __shared__ __align__(16) u16 ldsU[17920];

  const int tid  = threadIdx.x;
  const int lane = tid & 63;
  const int w    = tid >> 6;
  const int quad = lane >> 4;
  const int l16  = lane & 15;
  const int M0   = 32 * w;                      // block-local base row of wave
  const int gr   = blockIdx.x * 64 + M0;        // global base row of wave
  float* Sf = (float*)(ldsU + 9216) + w * (32 * 68);

  // ---- stage hid rows gr..gr+31 -> H bf16 (wave-local) ----
  #pragma unroll
  for (int i = 0; i < 8; i++) {
    int c = lane + 64 * i;                      // 0..511
    int lr = c >> 4, c4 = c & 15;
    float4 v = ((const float4*)hid)[(size_t)(gr + lr) * 16 + c4];
    *(uint2*)&ldsU[4608 + (M0 + lr) * 72 + c4 * 4] = make_uint2(pk2(v.x, v.y), pk2(v.z, v.w));
  }

  // ---- enc: x = relu(obs @ encW + encb), 2 m-tiles ----
  f32x4 ce[2][4];
  #pragma unroll
  for (int t = 0; t < 4; t++) {
    float bv = encb[16 * t + l16];
    ce[0][t] = (f32x4){bv, bv, bv, bv};
    ce[1][t] = (f32x4){bv, bv, bv, bv};
  }
  #pragma unroll
  for (int ks = 0; ks < 8; ks++) {
    short8 a[2];
    #pragma unroll
    for (int mt = 0; mt < 2; mt++) {
      const float* ap = obs + (size_t)(gr + 16 * mt + l16) * 256 + ks * 32 + quad * 8;
      float4 a0 = *(const float4*)ap, a1 = *(const float4*)(ap + 4);
      a[mt] = as_s8(make_uint4(pk2(a0.x, a0.y), pk2(a0.z, a0.w), pk2(a1.x, a1.y), pk2(a1.z, a1.w)));
    }
    #pragma unroll
    for (int t = 0; t < 4; t++) {
      short8 b = as_s8(*(const uint4*)&g_wbuf[ENCB + (16 * t + l16) * 264 + ks * 32 + quad * 8]);
      ce[0][t] = MFMA16(a[0], b, ce[0][t]);
      ce[1][t] = MFMA16(a[1], b, ce[1][t]);
    }
  }
  #pragma unroll
  for (int mt = 0; mt < 2; mt++)
    #pragma unroll
    for (int t = 0; t < 4; t++)
      #pragma unroll
      for (int r = 0; r < 4; r++)
        Sf[(16 * mt + quad * 4 + r) * 68 + 16 * t + l16] = fmaxf(ce[mt][t][r], 0.f);
  #pragma unroll
  for (int i = 0; i < 4; i++) {                 // transpose-pack x -> X
    int c = lane + 64 * i, lr = c >> 3, j = c & 7;
    const float* sp = &Sf[lr * 68 + 8 * j];
    float4 v0 = *(const float4*)sp, v1 = *(const float4*)(sp + 4);
    *(uint4*)&ldsU[(M0 + lr) * 72 + 8 * j] =
        make_uint4(pk2(v0.x, v0.y), pk2(v0.z, v0.w), pk2(v1.x, v1.y), pk2(v1.z, v1.w));
  }
  __syncthreads();   // X/H writes -> frag reads

  // ---- GRU (2 m-tiles share all B-frags) ----
  short8 ax[2][2], ah[2][2];
  #pragma unroll
  for (int mt = 0; mt < 2; mt++)
    #pragma unroll
    for (int ks = 0; ks < 2; ks++) {
      ax[mt][ks] = *(const short8*)&ldsU[(M0 + 16 * mt + l16) * 72 + ks * 32 + quad * 8];
      ah[mt][ks] = *(const short8*)&ldsU[4608 + (M0 + 16 * mt + l16) * 72 + ks * 32 + quad * 8];
    }
  #pragma unroll 1
  for (int u = 0; u < 4; u++) {
    f32x4 g6[2][6];
    #pragma unroll
    for (int mt = 0; mt < 2; mt++)
      #pragma unroll
      for (int t = 0; t < 6; t++) g6[mt][t] = (f32x4){0.f, 0.f, 0.f, 0.f};
    #pragma unroll
    for (int g = 0; g < 3; g++) {
      int row = 64 * g + 16 * u + l16;
      #pragma unroll
      for (int ks = 0; ks < 2; ks++) {
        short8 bi = as_s8(*(const uint4*)&g_wbuf[WIHB + row * 72 + ks * 32 + quad * 8]);
        short8 bh = as_s8(*(const uint4*)&g_wbuf[WHHB + row * 72 + ks * 32 + quad * 8]);
        #pragma unroll
        for (int mt = 0; mt < 2; mt++) {
          g6[mt][g]     = MFMA16(ax[mt][ks], bi, g6[mt][g]);
          g6[mt][3 + g] = MFMA16(ah[mt][ks], bh, g6[mt][3 + g]);
        }
      }
    }
    int nc = 16 * u + l16;
    float brz = g_bias[nc], bzz = g_bias[64 + nc], bni = g_bias[128 + nc], bnh = g_bias[192 + nc];
    #pragma unroll
    for (int mt = 0; mt < 2; mt++)
      #pragma unroll
      for (int r = 0; r < 4; r++) {
        int lr = 16 * mt + quad * 4 + r;
        float hp = blo(ldsU[4608 + (M0 + lr) * 72 + nc]);
        float rg = sigm(g6[mt][0][r] + g6[mt][3][r] + brz);
        float zg = sigm(g6[mt][1][r] + g6[mt][4][r] + bzz);
        float nn = tanhp(g6[mt][2][r] + bni + rg * (g6[mt][5][r] + bnh));
        Sf[lr * 68 + nc] = (1.f - zg) * nn + zg * hp;
      }
  }
  #pragma unroll
  for (int i = 0; i < 4; i++) {                 // transpose-pack h_out -> H
    int c = lane + 64 * i, lr = c >> 3, j = c & 7;
    const float* sp = &Sf[lr * 68 + 8 * j];
    float4 v0 = *(const float4*)sp, v1 = *(const float4*)(sp + 4);
    *(uint4*)&ldsU[4608 + (M0 + lr) * 72 + 8 * j] =
        make_uint4(pk2(v0.x, v0.y), pk2(v0.z, v0.w), pk2(v1.x, v1.y), pk2(v1.z, v1.w));
  }
  __syncthreads();   // h_out -> frag reads

  // ---- q,k,v (2 m-tiles share B) ----
  short8 hx[2][2];
  #pragma unroll
  for (int mt = 0; mt < 2; mt++)
    #pragma unroll
    for (int ks = 0; ks < 2; ks++)
      hx[mt][ks] = *(const short8*)&ldsU[4608 + (M0 + 16 * mt + l16) * 72 + ks * 32 + quad * 8];
  f32x4 cq[2][6];
  #pragma unroll
  for (int t = 0; t < 6; t++) {
    float bv = (t >= 4) ? vb[16 * (t - 4) + l16] : 0.f;
    cq[0][t] = (f32x4){bv, bv, bv, bv};
    cq[1][t] = (f32x4){bv, bv, bv, bv};
  }
  #pragma unroll
  for (int ks = 0; ks < 2; ks++)
    #pragma unroll
    for (int t = 0; t < 6; t++) {
      short8 b = as_s8(*(const uint4*)&g_wbuf[QKVB + (16 * t + l16) * 72 + ks * 32 + quad * 8]);
      cq[0][t] = MFMA16(hx[0][ks], b, cq[0][t]);
      cq[1][t] = MFMA16(hx[1][ks], b, cq[1][t]);
    }
  #pragma unroll
  for (int mt = 0; mt < 2; mt++) {
    #pragma unroll
    for (int t = 0; t < 4; t++)                 // q cols 0-31, k cols 32-63 (fp32)
      #pragma unroll
      for (int r = 0; r < 4; r++)
        Sf[(16 * mt + quad * 4 + r) * 68 + 16 * t + l16] = cq[mt][t][r];
    #pragma unroll
    for (int t = 4; t < 6; t++)                 // v -> X cols 32-63 (bf16)
      #pragma unroll
      for (int r = 0; r < 4; r++)
        ldsU[(M0 + 16 * mt + quad * 4 + r) * 72 + 32 + 16 * (t - 4) + l16] =
            (u16)pk2(fmaxf(cq[mt][t][r], 0.f), 0.f);
  }
  __syncthreads();   // v/q/k visible

  // ---- attention (wave-local; 2 lanes per row, 32 rows) ----
  {
    const int r_l = lane >> 1, s2 = lane & 1;
    const int gb = r_l & ~7, ri = r_l & 7;
    const float* fq = &Sf[r_l * 68];
    float sc[4];
    #pragma unroll
    for (int jj = 0; jj < 4; jj++) {
      int j = 4 * s2 + jj;
      const float* fk = &Sf[(gb + j) * 68 + 32];
      float d = 0.f;
      #pragma unroll
      for (int a4 = 0; a4 < 32; a4 += 4) {
        float4 q4 = *(const float4*)&fq[a4];
        float4 k4 = *(const float4*)&fk[a4];
        d += q4.x * k4.x + q4.y * k4.y + q4.z * k4.z + q4.w * k4.w;
      }
      sc[jj] = (j == ri) ? -1e30f : d;
    }
    float m = fmaxf(fmaxf(sc[0], sc[1]), fmaxf(sc[2], sc[3]));
    m = fmaxf(m, __shfl_xor(m, 1));
    float p[4], sum = 0.f;
    #pragma unroll
    for (int jj = 0; jj < 4; jj++) {
      int j = 4 * s2 + jj;
      p[jj] = (j == ri) ? 0.f : __expf(sc[jj] - m);
      sum += p[jj];
    }
    sum += __shfl_xor(sum, 1);
    float inv = 1.f / sum;
    #pragma unroll
    for (int jj = 0; jj < 4; jj++)
      Sf[r_l * 68 + 4 * s2 + jj] = p[jj] * inv;   // p overwrites q cols 0-7
    float xa[16];
    #pragma unroll
    for (int u = 0; u < 16; u++) xa[u] = 0.f;
    #pragma unroll
    for (int j = 0; j < 8; j++) {
      float aj = Sf[r_l * 68 + j];
      const u16* vp = &ldsU[(M0 + gb + j) * 72 + 32 + 16 * s2];
      uint4 v0 = *(const uint4*)vp, v1 = *(const uint4*)(vp + 8);
      xa[0]  += aj * blo(v0.x); xa[1]  += aj * bhi(v0.x);
      xa[2]  += aj * blo(v0.y); xa[3]  += aj * bhi(v0.y);
      xa[4]  += aj * blo(v0.z); xa[5]  += aj * bhi(v0.z);
      xa[6]  += aj * blo(v0.w); xa[7]  += aj * bhi(v0.w);
      xa[8]  += aj * blo(v1.x); xa[9]  += aj * bhi(v1.x);
      xa[10] += aj * blo(v1.y); xa[11] += aj * bhi(v1.y);
      xa[12] += aj * blo(v1.z); xa[13] += aj * bhi(v1.z);
      xa[14] += aj * blo(v1.w); xa[15] += aj * bhi(v1.w);
    }
    u16* xp = &ldsU[(M0 + r_l) * 72 + 16 * s2];   // xatt -> X cols 0-31
    *(uint4*)xp = make_uint4(pk2(xa[0], xa[1]), pk2(xa[2], xa[3]),
                             pk2(xa[4], xa[5]), pk2(xa[6], xa[7]));
    *(uint4*)(xp + 8) = make_uint4(pk2(xa[8], xa[9]),  pk2(xa[10], xa[11]),
                                   pk2(xa[12], xa[13]), pk2(xa[14], xa[15]));
  }
  __syncthreads();   // xatt -> frag reads

  // ---- dec: [h_out | xatt] @ decW + decb ----
  {
    float db = (l16 < NACT) ? decb[l16] : 0.f;
    f32x4 co[2] = {(f32x4){db, db, db, db}, (f32x4){db, db, db, db}};
    #pragma unroll
    for (int ks = 0; ks < 2; ks++) {
      short8 b = as_s8(*(const uint4*)&g_wbuf[DECB + l16 * 104 + ks * 32 + quad * 8]);
      #pragma unroll
      for (int mt = 0; mt < 2; mt++) {
        short8 a = *(const short8*)&ldsU[4608 + (M0 + 16 * mt + l16) * 72 + ks * 32 + quad * 8];
        co[mt] = MFMA16(a, b, co[mt]);
      }
    }
    short8 b2 = as_s8(*(const uint4*)&g_wbuf[DECB + l16 * 104 + 64 + quad * 8]);
    #pragma unroll
    for (int mt = 0; mt < 2; mt++) {
      short8 a2 = *(const short8*)&ldsU[(M0 + 16 * mt + l16) * 72 + quad * 8];
      co[mt] = MFMA16(a2, b2, co[mt]);
    }
    if (l16 < NACT)
      #pragma unroll
      for (int mt = 0; mt < 2; mt++)
        #pragma unroll
        for (int r = 0; r < 4; r++)
          out[(size_t)(gr + 16 * mt + quad * 4 + r) * NACT + l16] = co[mt][r];
  }

  // ---- h_out fp32 global store (from H bf16) ----
  {
    float* outH = out + (size_t)BTOT * NACT;
    #pragma unroll
    for (int i = 0; i < 4; i++) {
      int c = lane + 64 * i, lr = c >> 3, j = c & 7;
      uint4 u = *(const uint4*)&ldsU[4608 + (M0 + lr) * 72 + 8 * j];
      *(float4*)(outH + (size_t)(gr + lr) * 64 + 8 * j) =
          make_float4(blo(u.x), bhi(u.x), blo(u.y), bhi(u.y));
      *(float4*)(outH + (size_t)(gr + lr) * 64 + 8 * j + 4) =
          make_float4(blo(u.z), bhi(u.z), blo(u.w), bhi(u.w));
    }
  }
}

extern "C" void kernel_launch(void* const* d_in, const int* in_sizes, int n_in,
                              void* d_out, int out_size, void* d_ws, size_t ws_size,
                              hipStream_t stream) {
  (void)in_sizes; (void)n_in; (void)d_ws; (void)ws_size; (void)out_size;
  const float* obs  = (const float*)d_in[0];
  const float* hid  = (const float*)d_in[1];
  const float* encW = (const float*)d_in[2];
  const float* encb = (const float*)d_in[3];
  const float* Wih  = (const float*)d_in[4];
  const float* Whh  = (const float*)d_in[5];
  const float* bih  = (const float*)d_in[6];
  const float* bhh  = (const float*)d_in[7];
  const float* qW   = (const float*)d_in[8];
  const float* kW   = (const float*)d_in[9];
  const float* vW   = (const float*)d_in[10];
  const float* vb   = (const float*)d_in[11];
  const float* decW = (const float*)d_in[12];
  const float* decb = (const float*)d_in[13];
  float* out = (float*)d_out;

  prep<<<(WTOT + 255) / 256, 256, 0, stream>>>(encW, Wih, Whh, qW, kW, vW, decW, bih, bhh);
  commslave_main<<<BTOT / 64, 128, 0, stream>>>(obs, hid, encb, vb, decb, out);
}

// Round 8
// 149.131 us; speedup vs baseline: 1.0976x; 1.0341x over previous
//
#include <hip/hip_runtime.h>

// CommSlave — Round 8: r7 structure + FRAGMENT-ORDER weight images.
// Every B-frag load is now `uniform + lane*16` (one contiguous 1 KB wave
// request) instead of a 16-segment gather. Block = 128 thr = 2 waves =
// 64 rows; wave = 32 rows = 2 m-tiles sharing each B-frag. Grid = 1024.
// Fragment maps (verified r4-r7): A[m=lane&15][k=quad*8+j]; C/D col=lane&15,
// row=quad*4+reg. B-frag chunk layout: element lane*8+j = B[k=ks*32+quad*8+j][n].

#define NACT 14
#define BTOT 65536

typedef unsigned int  u32;
typedef unsigned short u16;
using short8 = __attribute__((ext_vector_type(8))) short;
using f32x4  = __attribute__((ext_vector_type(4))) float;

// frag-order image offsets (u16 units); each frag = 512 u16 = 1 KB
#define ENC0 0        // 32 frags: f = ks*4 + t        (ks<8, t<4)
#define WIH0 16384    // 24 frags: f = (u*3+g)*2 + ks  (u<4, g<3, ks<2)
#define WHH0 28672    // 24 frags: same
#define QKV0 40960    // 12 frags: f = t*2 + ks        (t<6: q0,q1,k0,k1,v0,v1)
#define DEC0 47104    //  3 frags: f = ks              (ks<3)
#define WTOT 48640

__device__ u16   g_wbuf[WTOT];
__device__ float g_bias[256];   // r: bih+bhh, z: bih+bhh, n_i: bih, n_h: bhh

__device__ __forceinline__ u32 f2bf_rne(float f){
  u32 x = __float_as_uint(f);
  return (x + 0x7fffu + ((x >> 16) & 1u)) >> 16;
}
__device__ __forceinline__ u32 pk2(float a, float b){
  u32 d;
  asm("v_cvt_pk_bf16_f32 %0, %1, %2" : "=v"(d) : "v"(a), "v"(b));
  return d;
}
__device__ __forceinline__ float blo(u32 u){ return __uint_as_float(u << 16); }
__device__ __forceinline__ float bhi(u32 u){ return __uint_as_float(u & 0xffff0000u); }
__device__ __forceinline__ float sigm(float x){ return 1.0f / (1.0f + __expf(-x)); }
__device__ __forceinline__ float tanhp(float x){ return 1.0f - 2.0f / (__expf(2.0f * x) + 1.0f); }
__device__ __forceinline__ short8 as_s8(uint4 v){ union { uint4 u; short8 s; } x; x.u = v; return x.s; }

#define MFMA16(a,b,c) __builtin_amdgcn_mfma_f32_16x16x32_bf16((a),(b),(c),0,0,0)

// ======================= prep: build frag-order bf16 images ==================
__global__ void prep(const float* __restrict__ encW, const float* __restrict__ Wih,
                     const float* __restrict__ Whh,  const float* __restrict__ qW,
                     const float* __restrict__ kW,   const float* __restrict__ vW,
                     const float* __restrict__ decW, const float* __restrict__ bih,
                     const float* __restrict__ bhh)
{
  int j = blockIdx.x * 256 + threadIdx.x;
  if (blockIdx.x == 0) {
    int n = threadIdx.x & 63, g = threadIdx.x >> 6;
    float v;
    if      (g == 0) v = bih[n]       + bhh[n];
    else if (g == 1) v = bih[64 + n]  + bhh[64 + n];
    else if (g == 2) v = bih[128 + n];
    else             v = bhh[128 + n];
    g_bias[threadIdx.x] = v;
  }
  if (j >= WTOT) return;
  int pos  = j & 511;
  int lane = pos >> 3, jj = pos & 7;
  int quad = lane >> 4, l16 = lane & 15;
  float val = 0.f;
  if (j < WIH0) {                         // ENC
    int f = j >> 9, ks = f >> 2, t = f & 3;
    int k = ks * 32 + quad * 8 + jj, n = 16 * t + l16;
    val = encW[k * 64 + n];
  } else if (j < WHH0) {                  // WIH
    int f = (j - WIH0) >> 9;
    int u = f / 6, g = (f >> 1) % 3, ks = f & 1;
    int wrow = 64 * g + 16 * u + l16, k = ks * 32 + quad * 8 + jj;
    val = Wih[wrow * 64 + k];
  } else if (j < QKV0) {                  // WHH
    int f = (j - WHH0) >> 9;
    int u = f / 6, g = (f >> 1) % 3, ks = f & 1;
    int wrow = 64 * g + 16 * u + l16, k = ks * 32 + quad * 8 + jj;
    val = Whh[wrow * 64 + k];
  } else if (j < DEC0) {                  // QKV
    int f = (j - QKV0) >> 9, t = f >> 1, ks = f & 1;
    int n = 16 * t + l16, mtx = n >> 5, nn = n & 31;
    int k = ks * 32 + quad * 8 + jj;
    val = (mtx == 0) ? qW[k * 32 + nn] * 0.17677669529663687f
        : (mtx == 1) ? kW[k * 32 + nn] : vW[k * 32 + nn];
  } else {                                // DEC
    int f = (j - DEC0) >> 9;
    int k = f * 32 + quad * 8 + jj, n = l16;
    if (n < 14) val = decW[k * 14 + n];
  }
  g_wbuf[j] = (u16)f2bf_rne(val);
}

// ======================= main ================================================
// LDS/block (35840 B): X bf16 [64][72] @u16 0 (x; cols 32-63 v, 0-31 xatt);
// H bf16 [64][72] @u16 4608 (hid -> h_out); Sf fp32 [32][68] per wave
// @byte 18432 + w*8704 (transpose scratch, then q cols 0-31 / k 32-63,
// p overwrites q cols 0-7).
__global__ __launch_bounds__(128, 2)
void commslave_main(const float* __restrict__ obs,  const float* __restrict__ hid,
                    const float* __restrict__ encb, const float* __restrict__ vb,
                    const float* __restrict__ decb, float* __restrict__ out)
{
  __shared__ __align__(16) u16 ldsU[17920];

  const int tid  = threadIdx.x;
  const int lane = tid & 63;
  const int w    = tid >> 6;
  const int quad = lane >> 4;
  const int l16  = lane & 15;
  const int M0   = 32 * w;
  const int gr   = blockIdx.x * 64 + M0;
  float* Sf = (float*)(ldsU + 9216) + w * (32 * 68);

  // ---- stage hid rows gr..gr+31 -> H bf16 (wave-local) ----
  #pragma unroll
  for (int i = 0; i < 8; i++) {
    int c = lane + 64 * i;
    int lr = c >> 4, c4 = c & 15;
    float4 v = ((const float4*)hid)[(size_t)(gr + lr) * 16 + c4];
    *(uint2*)&ldsU[4608 + (M0 + lr) * 72 + c4 * 4] = make_uint2(pk2(v.x, v.y), pk2(v.z, v.w));
  }

  // ---- enc: x = relu(obs @ encW + encb), 2 m-tiles ----
  f32x4 ce[2][4];
  #pragma unroll
  for (int t = 0; t < 4; t++) {
    float bv = encb[16 * t + l16];
    ce[0][t] = (f32x4){bv, bv, bv, bv};
    ce[1][t] = (f32x4){bv, bv, bv, bv};
  }
  #pragma unroll
  for (int ks = 0; ks < 8; ks++) {
    short8 a[2];
    #pragma unroll
    for (int mt = 0; mt < 2; mt++) {
      const float* ap = obs + (size_t)(gr + 16 * mt + l16) * 256 + ks * 32 + quad * 8;
      float4 a0 = *(const float4*)ap, a1 = *(const float4*)(ap + 4);
      a[mt] = as_s8(make_uint4(pk2(a0.x, a0.y), pk2(a0.z, a0.w), pk2(a1.x, a1.y), pk2(a1.z, a1.w)));
    }
    #pragma unroll
    for (int t = 0; t < 4; t++) {
      short8 b = as_s8(*(const uint4*)&g_wbuf[ENC0 + (ks * 4 + t) * 512 + lane * 8]);
      ce[0][t] = MFMA16(a[0], b, ce[0][t]);
      ce[1][t] = MFMA16(a[1], b, ce[1][t]);
    }
  }
  #pragma unroll
  for (int mt = 0; mt < 2; mt++)
    #pragma unroll
    for (int t = 0; t < 4; t++)
      #pragma unroll
      for (int r = 0; r < 4; r++)
        Sf[(16 * mt + quad * 4 + r) * 68 + 16 * t + l16] = fmaxf(ce[mt][t][r], 0.f);
  #pragma unroll
  for (int i = 0; i < 4; i++) {                 // transpose-pack x -> X
    int c = lane + 64 * i, lr = c >> 3, j = c & 7;
    const float* sp = &Sf[lr * 68 + 8 * j];
    float4 v0 = *(const float4*)sp, v1 = *(const float4*)(sp + 4);
    *(uint4*)&ldsU[(M0 + lr) * 72 + 8 * j] =
        make_uint4(pk2(v0.x, v0.y), pk2(v0.z, v0.w), pk2(v1.x, v1.y), pk2(v1.z, v1.w));
  }
  __syncthreads();   // X/H writes -> frag reads

  // ---- GRU (2 m-tiles share all B-frags) ----
  short8 ax[2][2], ah[2][2];
  #pragma unroll
  for (int mt = 0; mt < 2; mt++)
    #pragma unroll
    for (int ks = 0; ks < 2; ks++) {
      ax[mt][ks] = *(const short8*)&ldsU[(M0 + 16 * mt + l16) * 72 + ks * 32 + quad * 8];
      ah[mt][ks] = *(const short8*)&ldsU[4608 + (M0 + 16 * mt + l16) * 72 + ks * 32 + quad * 8];
    }
  #pragma unroll 1
  for (int u = 0; u < 4; u++) {
    f32x4 g6[2][6];
    #pragma unroll
    for (int mt = 0; mt < 2; mt++)
      #pragma unroll
      for (int t = 0; t < 6; t++) g6[mt][t] = (f32x4){0.f, 0.f, 0.f, 0.f};
    #pragma unroll
    for (int g = 0; g < 3; g++) {
      #pragma unroll
      for (int ks = 0; ks < 2; ks++) {
        int f = (u * 3 + g) * 2 + ks;
        short8 bi = as_s8(*(const uint4*)&g_wbuf[WIH0 + f * 512 + lane * 8]);
        short8 bh = as_s8(*(const uint4*)&g_wbuf[WHH0 + f * 512 + lane * 8]);
        #pragma unroll
        for (int mt = 0; mt < 2; mt++) {
          g6[mt][g]     = MFMA16(ax[mt][ks], bi, g6[mt][g]);
          g6[mt][3 + g] = MFMA16(ah[mt][ks], bh, g6[mt][3 + g]);
        }
      }
    }
    int nc = 16 * u + l16;
    float brz = g_bias[nc], bzz = g_bias[64 + nc], bni = g_bias[128 + nc], bnh = g_bias[192 + nc];
    #pragma unroll
    for (int mt = 0; mt < 2; mt++)
      #pragma unroll
      for (int r = 0; r < 4; r++) {
        int lr = 16 * mt + quad * 4 + r;
        float hp = blo(ldsU[4608 + (M0 + lr) * 72 + nc]);
        float rg = sigm(g6[mt][0][r] + g6[mt][3][r] + brz);
        float zg = sigm(g6[mt][1][r] + g6[mt][4][r] + bzz);
        float nn = tanhp(g6[mt][2][r] + bni + rg * (g6[mt][5][r] + bnh));
        Sf[lr * 68 + nc] = (1.f - zg) * nn + zg * hp;
      }
  }
  #pragma unroll
  for (int i = 0; i < 4; i++) {                 // transpose-pack h_out -> H
    int c = lane + 64 * i, lr = c >> 3, j = c & 7;
    const float* sp = &Sf[lr * 68 + 8 * j];
    float4 v0 = *(const float4*)sp, v1 = *(const float4*)(sp + 4);
    *(uint4*)&ldsU[4608 + (M0 + lr) * 72 + 8 * j] =
        make_uint4(pk2(v0.x, v0.y), pk2(v0.z, v0.w), pk2(v1.x, v1.y), pk2(v1.z, v1.w));
  }
  __syncthreads();   // h_out -> frag reads

  // ---- q,k,v (2 m-tiles share B) ----
  short8 hx[2][2];
  #pragma unroll
  for (int mt = 0; mt < 2; mt++)
    #pragma unroll
    for (int ks = 0; ks < 2; ks++)
      hx[mt][ks] = *(const short8*)&ldsU[4608 + (M0 + 16 * mt + l16) * 72 + ks * 32 + quad * 8];
  f32x4 cq[2][6];
  #pragma unroll
  for (int t = 0; t < 6; t++) {
    float bv = (t >= 4) ? vb[16 * (t - 4) + l16] : 0.f;
    cq[0][t] = (f32x4){bv, bv, bv, bv};
    cq[1][t] = (f32x4){bv, bv, bv, bv};
  }
  #pragma unroll
  for (int ks = 0; ks < 2; ks++)
    #pragma unroll
    for (int t = 0; t < 6; t++) {
      short8 b = as_s8(*(const uint4*)&g_wbuf[QKV0 + (t * 2 + ks) * 512 + lane * 8]);
      cq[0][t] = MFMA16(hx[0][ks], b, cq[0][t]);
      cq[1][t] = MFMA16(hx[1][ks], b, cq[1][t]);
    }
  #pragma unroll
  for (int mt = 0; mt < 2; mt++) {
    #pragma unroll
    for (int t = 0; t < 4; t++)                 // q cols 0-31, k cols 32-63 (fp32)
      #pragma unroll
      for (int r = 0; r < 4; r++)
        Sf[(16 * mt + quad * 4 + r) * 68 + 16 * t + l16] = cq[mt][t][r];
    #pragma unroll
    for (int t = 4; t < 6; t++)                 // v -> X cols 32-63 (bf16)
      #pragma unroll
      for (int r = 0; r < 4; r++)
        ldsU[(M0 + 16 * mt + quad * 4 + r) * 72 + 32 + 16 * (t - 4) + l16] =
            (u16)pk2(fmaxf(cq[mt][t][r], 0.f), 0.f);
  }
  __syncthreads();   // v/q/k visible

  // ---- attention (wave-local; 2 lanes per row, 32 rows) ----
  {
    const int r_l = lane >> 1, s2 = lane & 1;
    const int gb = r_l & ~7, ri = r_l & 7;
    const float* fq = &Sf[r_l * 68];
    float sc[4];
    #pragma unroll
    for (int jj = 0; jj < 4; jj++) {
      int j = 4 * s2 + jj;
      const float* fk = &Sf[(gb + j) * 68 + 32];
      float d = 0.f;
      #pragma unroll
      for (int a4 = 0; a4 < 32; a4 += 4) {
        float4 q4 = *(const float4*)&fq[a4];
        float4 k4 = *(const float4*)&fk[a4];
        d += q4.x * k4.x + q4.y * k4.y + q4.z * k4.z + q4.w * k4.w;
      }
      sc[jj] = (j == ri) ? -1e30f : d;
    }
    float m = fmaxf(fmaxf(sc[0], sc[1]), fmaxf(sc[2], sc[3]));
    m = fmaxf(m, __shfl_xor(m, 1));
    float p[4], sum = 0.f;
    #pragma unroll
    for (int jj = 0; jj < 4; jj++) {
      int j = 4 * s2 + jj;
      p[jj] = (j == ri) ? 0.f : __expf(sc[jj] - m);
      sum += p[jj];
    }
    sum += __shfl_xor(sum, 1);
    float inv = 1.f / sum;
    #pragma unroll
    for (int jj = 0; jj < 4; jj++)
      Sf[r_l * 68 + 4 * s2 + jj] = p[jj] * inv;
    float xa[16];
    #pragma unroll
    for (int u = 0; u < 16; u++) xa[u] = 0.f;
    #pragma unroll
    for (int j = 0; j < 8; j++) {
      float aj = Sf[r_l * 68 + j];
      const u16* vp = &ldsU[(M0 + gb + j) * 72 + 32 + 16 * s2];
      uint4 v0 = *(const uint4*)vp, v1 = *(const uint4*)(vp + 8);
      xa[0]  += aj * blo(v0.x); xa[1]  += aj * bhi(v0.x);
      xa[2]  += aj * blo(v0.y); xa[3]  += aj * bhi(v0.y);
      xa[4]  += aj * blo(v0.z); xa[5]  += aj * bhi(v0.z);
      xa[6]  += aj * blo(v0.w); xa[7]  += aj * bhi(v0.w);
      xa[8]  += aj * blo(v1.x); xa[9]  += aj * bhi(v1.x);
      xa[10] += aj * blo(v1.y); xa[11] += aj * bhi(v1.y);
      xa[12] += aj * blo(v1.z); xa[13] += aj * bhi(v1.z);
      xa[14] += aj * blo(v1.w); xa[15] += aj * bhi(v1.w);
    }
    u16* xp = &ldsU[(M0 + r_l) * 72 + 16 * s2];
    *(uint4*)xp = make_uint4(pk2(xa[0], xa[1]), pk2(xa[2], xa[3]),
                             pk2(xa[4], xa[5]), pk2(xa[6], xa[7]));
    *(uint4*)(xp + 8) = make_uint4(pk2(xa[8], xa[9]),  pk2(xa[10], xa[11]),
                                   pk2(xa[12], xa[13]), pk2(xa[14], xa[15]));
  }
  __syncthreads();   // xatt -> frag reads

  // ---- dec: [h_out | xatt] @ decW + decb ----
  {
    float db = (l16 < NACT) ? decb[l16] : 0.f;
    f32x4 co[2] = {(f32x4){db, db, db, db}, (f32x4){db, db, db, db}};
    #pragma unroll
    for (int ks = 0; ks < 2; ks++) {
      short8 b = as_s8(*(const uint4*)&g_wbuf[DEC0 + ks * 512 + lane * 8]);
      #pragma unroll
      for (int mt = 0; mt < 2; mt++) {
        short8 a = *(const short8*)&ldsU[4608 + (M0 + 16 * mt + l16) * 72 + ks * 32 + quad * 8];
        co[mt] = MFMA16(a, b, co[mt]);
      }
    }
    short8 b2 = as_s8(*(const uint4*)&g_wbuf[DEC0 + 2 * 512 + lane * 8]);
    #pragma unroll
    for (int mt = 0; mt < 2; mt++) {
      short8 a2 = *(const short8*)&ldsU[(M0 + 16 * mt + l16) * 72 + quad * 8];
      co[mt] = MFMA16(a2, b2, co[mt]);
    }
    if (l16 < NACT)
      #pragma unroll
      for (int mt = 0; mt < 2; mt++)
        #pragma unroll
        for (int r = 0; r < 4; r++)
          out[(size_t)(gr + 16 * mt + quad * 4 + r) * NACT + l16] = co[mt][r];
  }

  // ---- h_out fp32 global store (from H bf16) ----
  {
    float* outH = out + (size_t)BTOT * NACT;
    #pragma unroll
    for (int i = 0; i < 4; i++) {
      int c = lane + 64 * i, lr = c >> 3, j = c & 7;
      uint4 u = *(const uint4*)&ldsU[4608 + (M0 + lr) * 72 + 8 * j];
      *(float4*)(outH + (size_t)(gr + lr) * 64 + 8 * j) =
          make_float4(blo(u.x), bhi(u.x), blo(u.y), bhi(u.y));
      *(float4*)(outH + (size_t)(gr + lr) * 64 + 8 * j + 4) =
          make_float4(blo(u.z), bhi(u.z), blo(u.w), bhi(u.w));
    }
  }
}

extern "C" void kernel_launch(void* const* d_in, const int* in_sizes, int n_in,
                              void* d_out, int out_size, void* d_ws, size_t ws_size,
                              hipStream_t stream) {
  (void)in_sizes; (void)n_in; (void)d_ws; (void)ws_size; (void)out_size;
  const float* obs  = (const float*)d_in[0];
  const float* hid  = (const float*)d_in[1];
  const float* encW = (const float*)d_in[2];
  const float* encb = (const float*)d_in[3];
  const float* Wih  = (const float*)d_in[4];
  const float* Whh  = (const float*)d_in[5];
  const float* bih  = (const float*)d_in[6];
  const float* bhh  = (const float*)d_in[7];
  const float* qW   = (const float*)d_in[8];
  const float* kW   = (const float*)d_in[9];
  const float* vW   = (const float*)d_in[10];
  const float* vb   = (const float*)d_in[11];
  const float* decW = (const float*)d_in[12];
  const float* decb = (const float*)d_in[13];
  float* out = (float*)d_out;

  prep<<<(WTOT + 255) / 256, 256, 0, stream>>>(encW, Wih, Whh, qW, kW, vW, decW, bih, bhh);
  commslave_main<<<BTOT / 64, 128, 0, stream>>>(obs, hid, encb, vb, decb, out);
}